// Round 3
// baseline (639.205 us; speedup 1.0000x reference)
//
#include <hip/hip_runtime.h>

#define H 4096
#define NVOCAB 256

// 64-lane dot of one 4096-elem fp32 row with fp32 vec. Result on lane 0.
__device__ __forceinline__ float row_dot(const float* __restrict__ wrow,
                                         const float* __restrict__ vec,
                                         int lane) {
    const float4* wr = reinterpret_cast<const float4*>(wrow);
    const float4* xr = reinterpret_cast<const float4*>(vec);
    float acc = 0.f;
#pragma unroll
    for (int it = 0; it < 16; ++it) {
        int idx = it * 64 + lane;          // 1024 float4 per row
        float4 w = wr[idx];
        float4 x = xr[idx];
        acc += w.x * x.x + w.y * x.y + w.z * x.z + w.w * x.w;
    }
#pragma unroll
    for (int off = 32; off > 0; off >>= 1) acc += __shfl_down(acc, off, 64);
    return acc;
}

// One block (6 waves) per gate element i: waves 0..2 compute W_ih rows
// {i, H+i, 2H+i} . x ; waves 3..5 compute W_hh rows {i, H+i, 2H+i} . h.
// Thread 0 applies PyTorch GRU gate math (r,z,n order) and writes h'[i].
// Zero d_ws usage.
__global__ __launch_bounds__(384) void gru_layer_kernel(
    const float* __restrict__ Wih,
    const float* __restrict__ Whh,
    const float* __restrict__ bih,
    const float* __restrict__ bhh,
    const float* __restrict__ xbase,   // emb (layer0) or h0' (layer1)
    const int* __restrict__ inp, int use_inp,   // layer0: x = emb + inp[0]*H
    const float* __restrict__ hprev,   // hidden[layer]
    float* __restrict__ hout)          // d_out slot for h'[layer]
{
    __shared__ float lds[6];
    const int wave = threadIdx.x >> 6;   // 0..5
    const int lane = threadIdx.x & 63;
    const int i    = blockIdx.x;         // 0..4095

    const float* x = xbase + (use_inp ? (size_t)inp[0] * H : 0);
    const int g = (wave < 3) ? wave : (wave - 3);       // gate r/z/n
    const float* W    = (wave < 3) ? Wih : Whh;
    const float* vec  = (wave < 3) ? x   : hprev;
    const float* bias = (wave < 3) ? bih : bhh;

    float acc = row_dot(W + (size_t)(g * H + i) * H, vec, lane);
    if (lane == 0) lds[wave] = acc + bias[g * H + i];
    __syncthreads();

    if (threadIdx.x == 0) {
        float ir = lds[0], iz = lds[1], inn = lds[2];
        float hr = lds[3], hz = lds[4], hn  = lds[5];
        float r = 1.f / (1.f + __expf(-(ir + hr)));
        float z = 1.f / (1.f + __expf(-(iz + hz)));
        float n = tanhf(inn + r * hn);
        float h = hprev[i];
        hout[i] = (1.f - z) * n + z * h;
    }
}

// Decoder: 256 rows of W_dec . h1' + b_dec -> fp32 logits in d_out[0:256].
__global__ __launch_bounds__(256) void dec_kernel(
    const float* __restrict__ Wdec,
    const float* __restrict__ bdec,
    const float* __restrict__ vec,
    float* __restrict__ out)
{
    const int wave = threadIdx.x >> 6;
    const int lane = threadIdx.x & 63;
    const int row = blockIdx.x * 4 + wave;   // 64 blocks -> 256 rows
    float acc = row_dot(Wdec + (size_t)row * H, vec, lane);
    if (lane == 0) out[row] = acc + bdec[row];
}

extern "C" void kernel_launch(void* const* d_in, const int* in_sizes, int n_in,
                              void* d_out, int out_size, void* d_ws, size_t ws_size,
                              hipStream_t stream) {
    // setup_inputs() order (all float32 except inp which is int32):
    // 0 inp(1) 1 hidden(2*4096) 2 emb(256*4096)
    // 3 W_ih0 4 W_hh0 5 b_ih0 6 b_hh0
    // 7 W_ih1 8 W_hh1 9 b_ih1 10 b_hh1
    // 11 W_dec 12 b_dec
    const int*   inp    = (const int*)d_in[0];
    const float* hidden = (const float*)d_in[1];
    const float* emb    = (const float*)d_in[2];
    const float* Wih0   = (const float*)d_in[3];
    const float* Whh0   = (const float*)d_in[4];
    const float* bih0   = (const float*)d_in[5];
    const float* bhh0   = (const float*)d_in[6];
    const float* Wih1   = (const float*)d_in[7];
    const float* Whh1   = (const float*)d_in[8];
    const float* bih1   = (const float*)d_in[9];
    const float* bhh1   = (const float*)d_in[10];
    const float* Wdec   = (const float*)d_in[11];
    const float* bdec   = (const float*)d_in[12];

    float* out = (float*)d_out;  // [256 logits][h0' 4096][h1' 4096]
    float* h0o = out + NVOCAB;
    float* h1o = out + NVOCAB + H;

    // layer 0: x = emb[inp[0]], hprev = hidden[0] -> h0'
    gru_layer_kernel<<<H, 384, 0, stream>>>(
        Wih0, Whh0, bih0, bhh0, emb, inp, 1, hidden, h0o);
    // layer 1: x = h0', hprev = hidden[1] -> h1'
    gru_layer_kernel<<<H, 384, 0, stream>>>(
        Wih1, Whh1, bih1, bhh1, h0o, inp, 0, hidden + H, h1o);
    // decoder logits
    dec_kernel<<<NVOCAB / 4, 256, 0, stream>>>(Wdec, bdec, h1o, out);
}